// Round 16
// baseline (290.911 us; speedup 1.0000x reference)
//
#include <hip/hip_runtime.h>
#include <math.h>

#define D_MODEL 1024
#define DMEM 64
#define CAP 65536
#define SEQ 1024
#define NTOT 2048      // B*S
#define GATE_H 32
#define THETA 0.01f
#define ISQD 0.125f    // 1/sqrt(64)
#define LOG2E 1.4426950408889634f
#define LN2 0.6931471805599453f
#define NSPLIT 16
#define CSPL (CAP / NSPLIT)    // 4096
#define GN_BLOCKS 2048         // gcomb partials

// fused k_pre block ranges
#define PRE_POOL_N 8
#define PRE_PACKM_N (CAP / 64)        // 1024
#define PRE_PROJ_N (NTOT / 4)         // 512
#define PRE_PACKM_BASE PRE_POOL_N
#define PRE_PROJ_BASE (PRE_POOL_N + PRE_PACKM_N)
#define PRE_TOTAL (PRE_POOL_N + PRE_PACKM_N + PRE_PROJ_N)

typedef float f32x4 __attribute__((ext_vector_type(4)));
typedef short bf16x8 __attribute__((ext_vector_type(8)));
typedef unsigned int u32x4 __attribute__((ext_vector_type(4)));
typedef unsigned int u32x2 __attribute__((ext_vector_type(2)));

#define MFMA16(a, b, c) __builtin_amdgcn_mfma_f32_16x16x32_bf16(a, b, c, 0, 0, 0)

__device__ inline unsigned short f2bf(float f) {
  union { float f; unsigned u; } v; v.f = f;
  unsigned r = v.u + 0x7FFFu + ((v.u >> 16) & 1u);
  return (unsigned short)(r >> 16);
}
__device__ inline unsigned cvtpk(float lo, float hi) {
  unsigned r;
  asm("v_cvt_pk_bf16_f32 %0, %1, %2" : "=v"(r) : "v"(lo), "v"(hi));
  return r;
}
__device__ inline float exp2i(float x) {
  float r;
  asm("v_exp_f32 %0, %1" : "=v"(r) : "v"(x));
  return r;
}

// ---------------- K_pre: fused pool | packm | proj (verified R15) ------
__global__ __launch_bounds__(256) void k_pre(const float* __restrict__ x,
    const float* __restrict__ mem,
    const float* __restrict__ Wk, const float* __restrict__ bk,
    const float* __restrict__ Wv, const float* __restrict__ bv,
    float* __restrict__ pooled, float* __restrict__ vout,
    unsigned short* __restrict__ kb, unsigned short* __restrict__ kbT,
    unsigned short* __restrict__ Msb, unsigned short* __restrict__ MsbT) {
  __shared__ __align__(16) char smem[16384];
  int tid = threadIdx.x;
  int bid = blockIdx.x;

  if (bid < PRE_POOL_N) {
    int idx = bid * 256 + tid;
    int b = idx >> 10, j = idx & 1023;
    const float* base = x + (size_t)b * SEQ * D_MODEL + j;
    float s = 0.f;
    for (int t = 0; t < SEQ; ++t) s += base[(size_t)t * D_MODEL];
    pooled[idx] = s * (1.0f / SEQ);
    return;
  }

  if (bid < PRE_PROJ_BASE) {
    short (*tile)[72] = (short(*)[72])smem;
    int c0 = (bid - PRE_PACKM_BASE) * 64;
    int r = tid >> 2, dp = (tid & 3) * 16;
    const float4* src = (const float4*)(mem + (size_t)(c0 + r) * DMEM + dp);
    float4 q0 = src[0], q1 = src[1], q2 = src[2], q3 = src[3];
    float va[16] = {q0.x, q0.y, q0.z, q0.w, q1.x, q1.y, q1.z, q1.w,
                    q2.x, q2.y, q2.z, q2.w, q3.x, q3.y, q3.z, q3.w};
    const float s1 = ISQD * LOG2E;
    union { unsigned short s[16]; u32x4 v[2]; } o;
#pragma unroll
    for (int j = 0; j < 16; ++j) o.s[j] = f2bf(va[j] * s1);
    *(u32x4*)(Msb + (size_t)(c0 + r) * DMEM + dp) = o.v[0];
    *(u32x4*)(Msb + (size_t)(c0 + r) * DMEM + dp + 8) = o.v[1];
#pragma unroll
    for (int j = 0; j < 16; ++j) tile[dp + j][r] = (short)f2bf(va[j] * ISQD);
    __syncthreads();
    int d2 = tid >> 2, cp = (tid & 3) * 16;
    u32x4 t0 = *(const u32x4*)&tile[d2][cp];
    u32x4 t1 = *(const u32x4*)&tile[d2][cp + 8];
    *(u32x4*)(MsbT + (size_t)d2 * CAP + c0 + cp) = t0;
    *(u32x4*)(MsbT + (size_t)d2 * CAP + c0 + cp + 8) = t1;
    return;
  }

  float* xs = (float*)smem;
  int r = tid >> 6, j = tid & 63;
  int nb = (bid - PRE_PROJ_BASE) * 4;
  const float4* xr = (const float4*)(x + (size_t)nb * D_MODEL);
  float4* xs4 = (float4*)xs;
#pragma unroll
  for (int q = 0; q < 4; ++q) xs4[tid + 256 * q] = xr[tid + 256 * q];
  __syncthreads();
  float ak = bk[j], av = bv[j];
  const float* xrow = xs + r * D_MODEL;
#pragma unroll 8
  for (int i = 0; i < D_MODEL; ++i) {
    float xv = xrow[i];
    ak = fmaf(xv, Wk[i * DMEM + j], ak);
    av = fmaf(xv, Wv[i * DMEM + j], av);
  }
  int n = nb + r;
  vout[n * DMEM + j] = av;
  kb[n * DMEM + j] = f2bf(ak);
  kbT[(size_t)j * NTOT + n] = f2bf(ak * LN2);
}

// ---------------- K3: gates -> alpha, eta (verified R14; launched late) ----
__global__ __launch_bounds__(256) void k_gates(const float* __restrict__ pooled,
    const float* __restrict__ fw1, const float* __restrict__ fb1,
    const float* __restrict__ fw2, const float* __restrict__ fb2,
    const float* __restrict__ dw1, const float* __restrict__ db1,
    const float* __restrict__ dw2, const float* __restrict__ db2,
    float* __restrict__ scal) {
  __shared__ float hsh[2][2][GATE_H];
  __shared__ float outs[2][2];
  int t = threadIdx.x;
  int wv = t >> 6, lane = t & 63;
  int gate = wv >> 1, b = wv & 1;
  int h = lane & 31, half = lane >> 5;
  const float* w1 = gate ? dw1 : fw1;
  const float* b1 = gate ? db1 : fb1;
  const float* prow = pooled + b * D_MODEL;
  float z = 0.f;
  for (int i = half * 512; i < half * 512 + 512; ++i)
    z = fmaf(prow[i], w1[i * GATE_H + h], z);
  z += __shfl_xor(z, 32, 64);
  z += b1[h];
  float sig = 1.f / (1.f + __expf(-z));
  if (half == 0) hsh[gate][b][h] = z * sig;
  __syncthreads();
  if (t < 4) {
    int gg = t >> 1, bb = t & 1;
    const float* w2 = gg ? dw2 : fw2;
    float zz = gg ? db2[0] : fb2[0];
    for (int hh = 0; hh < GATE_H; ++hh) zz += hsh[gg][bb][hh] * w2[hh];
    outs[gg][bb] = 1.f / (1.f + __expf(-zz));
  }
  __syncthreads();
  if (t == 0) {
    scal[0] = 0.5f * (outs[0][0] + outs[0][1]);  // alpha
    scal[1] = 0.5f * (outs[1][0] + outs[1][1]);  // eta
  }
}

// ---------------- K4: MFMA forward v10 + setprio (body verified R14/R15) -----
__global__ __launch_bounds__(256, 4) void k_fwd10(
    const unsigned short* __restrict__ kb,
    const unsigned short* __restrict__ Msb,
    const unsigned short* __restrict__ MsbT,
    float* __restrict__ l_s, float* __restrict__ r_s) {
  __shared__ __align__(16) char smem[35840];
  __shared__ float esh[4][32];
  short* Mt  = (short*)smem;                    // [128][72]
  short* MTt = Mt + 128 * 72;                   // [64][136]
  int tid = threadIdx.x;
  int wv = tid >> 6, lane = tid & 63;
  int u = lane >> 4, p = lane & 15;
  int sp = blockIdx.x & 15, ng = blockIdx.x >> 4;
  int n0 = ng * 32;

  bf16x8 bkf[2][2];
#pragma unroll
  for (int nf = 0; nf < 2; ++nf) {
    const unsigned short* kbase = kb + (size_t)(n0 + nf * 16 + p) * DMEM + u * 8;
    bkf[nf][0] = *(const bf16x8*)(kbase);
    bkf[nf][1] = *(const bf16x8*)(kbase + 32);
  }

  int mc = tid >> 3, mdh = tid & 7;
  int td = tid >> 4, tch = tid & 15;
  int c0base = sp * CSPL;
  u32x4 sM[4], sT[4];
#pragma unroll
  for (int q = 0; q < 4; ++q) {
    sM[q] = *(const u32x4*)(Msb + (size_t)(c0base + mc + 32 * q) * DMEM + mdh * 8);
    sT[q] = *(const u32x4*)(MsbT + (size_t)(td + 16 * q) * CAP + c0base + tch * 8);
  }

  f32x4 racc[4][2];
#pragma unroll
  for (int df = 0; df < 4; ++df)
#pragma unroll
    for (int nf = 0; nf < 2; ++nf) racc[df][nf] = (f32x4){0.f, 0.f, 0.f, 0.f};
  float esum0 = 0.f, esum1 = 0.f;

  int sA = ((u & 1) << 5) + p;
  int sB = sA + 16;
  bool hiCf = (u >= 2);

  const int NT = CSPL / 128;  // 32
  for (int it = 0; it < NT; ++it) {
    __syncthreads();
#pragma unroll
    for (int q = 0; q < 4; ++q) {
      *(u32x4*)(Mt + (mc + 32 * q) * 72 + mdh * 8) = sM[q];
      *(u32x4*)(MTt + (td + 16 * q) * 136 + tch * 8) = sT[q];
    }
    __syncthreads();
    int itn = (it + 1 < NT) ? it + 1 : it;
    int c0n = c0base + itn * 128;
#pragma unroll
    for (int q = 0; q < 4; ++q) {
      sM[q] = *(const u32x4*)(Msb + (size_t)(c0n + mc + 32 * q) * DMEM + mdh * 8);
      sT[q] = *(const u32x4*)(MsbT + (size_t)(td + 16 * q) * CAP + c0n + tch * 8);
    }
    f32x4 s[2][2];
    __builtin_amdgcn_s_setprio(1);
#pragma unroll
    for (int cf = 0; cf < 2; ++cf) {
      bf16x8 a0 = *(const bf16x8*)(Mt + (wv * 32 + cf * 16 + p) * 72 + u * 8);
      bf16x8 a1 = *(const bf16x8*)(Mt + (wv * 32 + cf * 16 + p) * 72 + 32 + u * 8);
#pragma unroll
      for (int nf = 0; nf < 2; ++nf) {
        f32x4 acc = (f32x4){0.f, 0.f, 0.f, 0.f};
        acc = MFMA16(a0, bkf[nf][0], acc);
        acc = MFMA16(a1, bkf[nf][1], acc);
        s[cf][nf] = acc;
      }
    }
    __builtin_amdgcn_s_setprio(0);
    bf16x8 aTf[4];
#pragma unroll
    for (int df = 0; df < 4; ++df)
      aTf[df] = *(const bf16x8*)(MTt + (df * 16 + p) * 136 + wv * 32 + u * 8);
#pragma unroll
    for (int nf = 0; nf < 2; ++nf) {
      unsigned q0t0, q0t1, q1t0, q1t1;
      {
        float e0 = exp2i(s[0][nf].x), e1 = exp2i(s[0][nf].y);
        float e2 = exp2i(s[0][nf].z), e3 = exp2i(s[0][nf].w);
        float t4 = (e0 + e1) + (e2 + e3);
        if (nf == 0) esum0 += t4; else esum1 += t4;
        q0t0 = cvtpk(e0, e1); q0t1 = cvtpk(e2, e3);
      }
      {
        float e0 = exp2i(s[1][nf].x), e1 = exp2i(s[1][nf].y);
        float e2 = exp2i(s[1][nf].z), e3 = exp2i(s[1][nf].w);
        float t4 = (e0 + e1) + (e2 + e3);
        if (nf == 0) esum0 += t4; else esum1 += t4;
        q1t0 = cvtpk(e0, e1); q1t1 = cvtpk(e2, e3);
      }
      unsigned a0 = (unsigned)__shfl((int)q0t0, sA, 64);
      unsigned a1 = (unsigned)__shfl((int)q0t1, sA, 64);
      unsigned a2 = (unsigned)__shfl((int)q0t0, sB, 64);
      unsigned a3 = (unsigned)__shfl((int)q0t1, sB, 64);
      unsigned b0 = (unsigned)__shfl((int)q1t0, sA, 64);
      unsigned b1 = (unsigned)__shfl((int)q1t1, sA, 64);
      unsigned b2 = (unsigned)__shfl((int)q1t0, sB, 64);
      unsigned b3 = (unsigned)__shfl((int)q1t1, sB, 64);
      u32x4 bw4 = {hiCf ? b0 : a0, hiCf ? b1 : a1,
                   hiCf ? b2 : a2, hiCf ? b3 : a3};
      bf16x8 w = __builtin_bit_cast(bf16x8, bw4);
      __builtin_amdgcn_s_setprio(1);
#pragma unroll
      for (int df = 0; df < 4; ++df)
        racc[df][nf] = MFMA16(aTf[df], w, racc[df][nf]);
      __builtin_amdgcn_s_setprio(0);
    }
  }

  esum0 += __shfl_xor(esum0, 16, 64);
  esum0 += __shfl_xor(esum0, 32, 64);
  esum1 += __shfl_xor(esum1, 16, 64);
  esum1 += __shfl_xor(esum1, 32, 64);
  if (u == 0) {
    esh[wv][p] = esum0;
    esh[wv][16 + p] = esum1;
  }
  __syncthreads();
  if (tid < 32) {
    float l = (esh[0][tid] + esh[1][tid]) + (esh[2][tid] + esh[3][tid]);
    l_s[sp * NTOT + n0 + tid] = l;
  }
  float* rt = (float*)smem;  // [4][64][33] = 33792 <= 35840
#pragma unroll
  for (int df = 0; df < 4; ++df)
#pragma unroll
    for (int nf = 0; nf < 2; ++nf)
#pragma unroll
      for (int r = 0; r < 4; ++r)
        rt[(wv * 64 + df * 16 + 4 * u + r) * 33 + nf * 16 + p] = racc[df][nf][r];
  __syncthreads();
  int n = tid >> 3;
  int d8 = (tid & 7) * 8;
  float o[8];
#pragma unroll
  for (int q = 0; q < 8; ++q)
    o[q] = (rt[(0 * 64 + d8 + q) * 33 + n] + rt[(1 * 64 + d8 + q) * 33 + n]) +
           (rt[(2 * 64 + d8 + q) * 33 + n] + rt[(3 * 64 + d8 + q) * 33 + n]);
  float* dst = r_s + ((size_t)sp * NTOT + n0 + n) * DMEM + d8;
  *(float4*)(dst) = (float4){o[0], o[1], o[2], o[3]};
  *(float4*)(dst + 4) = (float4){o[4], o[5], o[6], o[7]};
}

// ---------------- K5: combine splits, loss, g (bf16), gdotr (verified) ----
__global__ __launch_bounds__(256) void k_comb(
    const float* __restrict__ l_s, const float* __restrict__ r_s,
    const float* __restrict__ v,
    unsigned short* __restrict__ gb, unsigned short* __restrict__ gbT,
    float* __restrict__ gdr8, float* __restrict__ linv,
    float* __restrict__ lossp) {
  __shared__ float lsum[4];
  int tid = threadIdx.x;
  int nl = tid >> 6, dd = tid & 63;
  int n = blockIdx.x * 4 + nl;
  float l = 0.f;
#pragma unroll
  for (int s = 0; s < NSPLIT; ++s) l += l_s[s * NTOT + n];
  float r = 0.f;
#pragma unroll
  for (int s = 0; s < NSPLIT; ++s)
    r += r_s[((size_t)s * NTOT + n) * DMEM + dd];
  float li = 1.f / l;
  float ret = r * li * 8.0f;   // MsbT carried ISQD -> compensate exactly
  float vv = v[n * DMEM + dd];
  const float c0 = 2.f / (float)(NTOT * DMEM);
  float diff = ret - vv;
  float gv = c0 * diff;
  gb[n * DMEM + dd] = f2bf(gv);
  gbT[dd * NTOT + n] = f2bf(gv);
  float gr = gv * ret;
  float lp = diff * diff;
#pragma unroll
  for (int off = 1; off < 64; off <<= 1) {
    gr += __shfl_xor(gr, off, 64);
    lp += __shfl_xor(lp, off, 64);
  }
  if (dd == 0) {
    gdr8[n] = gr * (ISQD * LOG2E);
    linv[n] = li;
    lsum[nl] = lp;
  }
  __syncthreads();
  if (tid == 0)
    lossp[blockIdx.x] =
        (lsum[0] + lsum[1] + lsum[2] + lsum[3]) * (1.f / (float)(NTOT * DMEM));
}

// ---------------- K6: MFMA backward v7 + setprio (body verified R10) -------
__global__ __launch_bounds__(256, 2) void k_bwd7(
    const unsigned short* __restrict__ kb, const unsigned short* __restrict__ kbT,
    const unsigned short* __restrict__ gb, const unsigned short* __restrict__ gbT,
    const unsigned short* __restrict__ Msb,
    const float* __restrict__ linv, const float* __restrict__ gdr8,
    float* __restrict__ gradf, unsigned short* __restrict__ gradh) {
  __shared__ __align__(16) short kt[32][72];
  __shared__ __align__(16) short gt[32][72];
  __shared__ __align__(16) short tT[2][64][40];   // [ktT, gtT]
  __shared__ unsigned wct[4][2][1280];            // per-wave [64c][20] w / coef
  int tid = threadIdx.x;
  int wv = tid >> 6, lane = tid & 63;
  int u = lane >> 4, p = lane & 15;
  int half = blockIdx.x & 1;
  int cw = (blockIdx.x >> 1) * 256 + wv * 64;
  int nbase = half * (NTOT / 2);
  unsigned* wtp = wct[wv][0];
  unsigned* ctp = wct[wv][1];

  bf16x8 bM[4][2];
#pragma unroll
  for (int cf = 0; cf < 4; ++cf) {
    const unsigned short* mb = Msb + (size_t)(cw + cf * 16 + p) * DMEM + u * 8;
    bM[cf][0] = *(const bf16x8*)(mb);
    bM[cf][1] = *(const bf16x8*)(mb + 32);
  }

  f32x4 gacc[4][4];
#pragma unroll
  for (int cf = 0; cf < 4; ++cf)
#pragma unroll
    for (int df = 0; df < 4; ++df) gacc[cf][df] = (f32x4){0.f, 0.f, 0.f, 0.f};

  int sn = tid >> 3, sdh = tid & 7;
  int sd = tid >> 2, sch = tid & 3;

  u32x4 rk  = *(const u32x4*)(kb + (size_t)(nbase + sn) * DMEM + sdh * 8);
  u32x4 rg  = *(const u32x4*)(gb + (size_t)(nbase + sn) * DMEM + sdh * 8);
  u32x4 rkT = *(const u32x4*)(kbT + (size_t)sd * NTOT + nbase + sch * 8);
  u32x4 rgT = *(const u32x4*)(gbT + (size_t)sd * NTOT + nbase + sch * 8);

  const int NT = (NTOT / 2) / 32;  // 32
  for (int it = 0; it < NT; ++it) {
    int n0 = nbase + it * 32;
    __syncthreads();
    *(u32x4*)&kt[sn][sdh * 8] = rk;
    *(u32x4*)&gt[sn][sdh * 8] = rg;
    *(u32x4*)&tT[0][sd][sch * 8] = rkT;
    *(u32x4*)&tT[1][sd][sch * 8] = rgT;
    __syncthreads();
    {
      int n0n = (it + 1 < NT) ? n0 + 32 : n0;
      rk  = *(const u32x4*)(kb + (size_t)(n0n + sn) * DMEM + sdh * 8);
      rg  = *(const u32x4*)(gb + (size_t)(n0n + sn) * DMEM + sdh * 8);
      rkT = *(const u32x4*)(kbT + (size_t)sd * NTOT + n0n + sch * 8);
      rgT = *(const u32x4*)(gbT + (size_t)sd * NTOT + n0n + sch * 8);
    }
    asm volatile("" ::: "memory");
#pragma unroll
    for (int nf = 0; nf < 2; ++nf) {
      bf16x8 ka0 = *(const bf16x8*)&kt[nf * 16 + p][u * 8];
      bf16x8 ka1 = *(const bf16x8*)&kt[nf * 16 + p][u * 8 + 32];
      bf16x8 ga0 = *(const bf16x8*)&gt[nf * 16 + p][u * 8];
      bf16x8 ga1 = *(const bf16x8*)&gt[nf * 16 + p][u * 8 + 32];
      float4 lv = *(const float4*)(linv + n0 + nf * 16 + u * 4);
      float4 dv = *(const float4*)(gdr8 + n0 + nf * 16 + u * 4);
#pragma unroll
      for (int cf = 0; cf < 4; ++cf) {
        __builtin_amdgcn_s_setprio(1);
        f32x4 s = (f32x4){0.f, 0.f, 0.f, 0.f};
        s = MFMA16(ka0, bM[cf][0], s);
        s = MFMA16(ka1, bM[cf][1], s);
        f32x4 pg = (f32x4){0.f, 0.f, 0.f, 0.f};
        pg = MFMA16(ga0, bM[cf][0], pg);
        pg = MFMA16(ga1, bM[cf][1], pg);
        __builtin_amdgcn_s_setprio(0);
        float w0 = exp2i(s.x) * lv.x;
        float w1 = exp2i(s.y) * lv.y;
        float w2 = exp2i(s.z) * lv.z;
        float w3 = exp2i(s.w) * lv.w;
        float c0v = w0 * (pg.x - dv.x);
        float c1v = w1 * (pg.y - dv.y);
        float c2v = w2 * (pg.z - dv.z);
        float c3v = w3 * (pg.w - dv.w);
        wtp[(cf * 16 + p) * 20 + nf * 8 + 2 * u]     = cvtpk(w0, w1);
        wtp[(cf * 16 + p) * 20 + nf * 8 + 2 * u + 1] = cvtpk(w2, w3);
        ctp[(cf * 16 + p) * 20 + nf * 8 + 2 * u]     = cvtpk(c0v, c1v);
        ctp[(cf * 16 + p) * 20 + nf * 8 + 2 * u + 1] = cvtpk(c2v, c3v);
      }
    }
    asm volatile("" ::: "memory");
    u32x4 aw4[4], ac4[4];
#pragma unroll
    for (int cf = 0; cf < 4; ++cf) {
      aw4[cf] = *(const u32x4*)(wtp + (cf * 16 + p) * 20 + u * 4);
      ac4[cf] = *(const u32x4*)(ctp + (cf * 16 + p) * 20 + u * 4);
    }
    asm volatile("" ::: "memory");
    __builtin_amdgcn_s_setprio(1);
#pragma unroll
    for (int df = 0; df < 4; ++df) {
      bf16x8 bg = *(const bf16x8*)&tT[1][df * 16 + p][u * 8];
      bf16x8 bk2 = *(const bf16x8*)&tT[0][df * 16 + p][u * 8];
#pragma unroll
      for (int cf = 0; cf < 4; ++cf) {
        gacc[cf][df] = MFMA16(__builtin_bit_cast(bf16x8, aw4[cf]), bg, gacc[cf][df]);
        gacc[cf][df] = MFMA16(__builtin_bit_cast(bf16x8, ac4[cf]), bk2, gacc[cf][df]);
      }
    }
    __builtin_amdgcn_s_setprio(0);
  }

  if (half == 0) {
#pragma unroll
    for (int cf = 0; cf < 4; ++cf)
#pragma unroll
      for (int df = 0; df < 4; ++df)
#pragma unroll
        for (int r = 0; r < 4; ++r)
          gradf[(size_t)(cw + cf * 16 + 4 * u + r) * DMEM + df * 16 + p] =
              gacc[cf][df][r];
  } else {
#pragma unroll
    for (int cf = 0; cf < 4; ++cf)
#pragma unroll
      for (int df = 0; df < 4; ++df)
#pragma unroll
        for (int r = 0; r < 4; ++r)
          gradh[(size_t)(cw + cf * 16 + 4 * u + r) * DMEM + df * 16 + p] =
              f2bf(gacc[cf][df][r]);
  }
}

// ---------------- K6b: grad = gradf + gradh; gnsq partials (verified R10) ----
__global__ __launch_bounds__(256) void k_gcomb(float* __restrict__ grad,
                                               const unsigned short* __restrict__ gradh,
                                               float* __restrict__ gnsqp) {
  __shared__ float red[4];
  int tid = threadIdx.x;
  size_t base = (size_t)blockIdx.x * 2048 + tid;
  float ss = 0.f;
#pragma unroll
  for (int j = 0; j < 8; ++j) {
    size_t i = base + (size_t)j * 256;
    unsigned hv = ((unsigned)gradh[i]) << 16;
    float v = grad[i] + __builtin_bit_cast(float, hv);
    grad[i] = v;
    ss = fmaf(v, v, ss);
  }
#pragma unroll
  for (int off = 1; off < 64; off <<= 1) ss += __shfl_xor(ss, off, 64);
  if ((tid & 63) == 0) red[tid >> 6] = ss;
  __syncthreads();
  if (tid == 0) gnsqp[blockIdx.x] = (red[0] + red[1]) + (red[2] + red[3]);
}

// ---------------- K7: final scalar reduce ----------------
__global__ __launch_bounds__(256) void k_fin(const float* __restrict__ gnsqp,
                                             const float* __restrict__ lossp,
                                             float* __restrict__ scal) {
  __shared__ float sh[8];
  int tid = threadIdx.x;
  float s1 = 0.f, s2 = 0.f;
  for (int i = tid; i < GN_BLOCKS; i += 256) s1 += gnsqp[i];
  for (int i = tid; i < NTOT / 4; i += 256) s2 += lossp[i];
#pragma unroll
  for (int off = 1; off < 64; off <<= 1) {
    s1 += __shfl_xor(s1, off, 64);
    s2 += __shfl_xor(s2, off, 64);
  }
  if ((tid & 63) == 0) { sh[(tid >> 6) * 2] = s1; sh[(tid >> 6) * 2 + 1] = s2; }
  __syncthreads();
  if (tid == 0) {
    float gnsq = sh[0] + sh[2] + sh[4] + sh[6];
    float loss = sh[1] + sh[3] + sh[5] + sh[7];
    float gn = sqrtf(gnsq);
    float clip = (gn > 1.0f) ? (1.0f / gn) : 1.0f;
    scal[2] = THETA * clip;
    scal[3] = loss;
  }
}

// ---------------- K8: M_new / S_new / loss write ----------------
__global__ __launch_bounds__(256) void k_upd(const float* __restrict__ mem,
    const float* __restrict__ momS, const float* __restrict__ grad,
    const float* __restrict__ scal, float* __restrict__ dout) {
  size_t i = (size_t)blockIdx.x * 256 + threadIdx.x;
  float oma = 1.f - scal[0];
  float eta = scal[1];
  float th = scal[2];
  if (i == 0) dout[0] = scal[3];
  float gr = grad[i];
  float sn = fmaf(-th, gr, eta * momS[i]);
  dout[1 + (size_t)CAP * DMEM + i] = sn;       // S_new (in-place over grad)
  dout[1 + i] = fmaf(oma, mem[i], sn);         // M_new
}

extern "C" void kernel_launch(void* const* d_in, const int* in_sizes, int n_in,
                              void* d_out, int out_size, void* d_ws, size_t ws_size,
                              hipStream_t stream) {
  const float* x    = (const float*)d_in[0];
  const float* mem  = (const float*)d_in[1];
  const float* momS = (const float*)d_in[2];
  const float* Wk   = (const float*)d_in[3];
  const float* bk   = (const float*)d_in[4];
  const float* Wv   = (const float*)d_in[5];
  const float* bv   = (const float*)d_in[6];
  const float* fw1  = (const float*)d_in[7];
  const float* fb1  = (const float*)d_in[8];
  const float* fw2  = (const float*)d_in[9];
  const float* fb2  = (const float*)d_in[10];
  const float* dw1  = (const float*)d_in[11];
  const float* db1  = (const float*)d_in[12];
  const float* dw2  = (const float*)d_in[13];
  const float* db2  = (const float*)d_in[14];

  float* out = (float*)d_out;
  float* wsf = (float*)d_ws;

  // ws scratch (~1.6 MB)
  float* scal   = wsf;                    // 16
  float* pooled = wsf + 16;               // 2048
  float* vbuf   = wsf + 2064;             // 131072
  float* gdr8   = vbuf + 131072;          // 2048
  float* linvb  = gdr8 + 2048;            // 2048
  float* lsb    = linvb + 2048;           // NSPLIT*2048 = 32768
  float* lossp  = lsb + 32768;            // 512
  float* gnsqp  = lossp + 512;            // 2048
  unsigned short* kb  = (unsigned short*)(gnsqp + 2048);  // 131072 shorts each
  unsigned short* kbT = kb + 131072;
  unsigned short* gb  = kbT + 131072;
  unsigned short* gbT = gb + 131072;

  // Msb+MsbT at out+0 (loss written last by k_upd) -> gradh (aliasing dead
  // MsbT) never overlaps grad.
  unsigned short* Msb   = (unsigned short*)out;          // [c][d], 8 MB
  unsigned short* MsbT  = Msb + (size_t)CAP * DMEM;      // [d][c], 8 MB
  unsigned short* gradh = MsbT;                          // bf16 half1 grad (reuse)
  // S_new slot: r_s (8 MB, dead before grad), then grad
  float* rsb  = out + 4 + (size_t)CAP * DMEM + 4;        // 16 splits * 2048 * 64
  float* grad = out + 1 + (size_t)CAP * DMEM;

  k_pre  <<<PRE_TOTAL, 256, 0, stream>>>(x, mem, Wk, bk, Wv, bv,
                                         pooled, vbuf, kb, kbT, Msb, MsbT);
  k_fwd10<<<(NTOT / 32) * NSPLIT, 256, 0, stream>>>(kb, Msb, MsbT, lsb, rsb);
  k_comb <<<NTOT / 4, 256, 0, stream>>>(lsb, rsb, vbuf, gb, gbT, gdr8, linvb, lossp);
  k_gates<<<1, 256, 0, stream>>>(pooled, fw1, fb1, fw2, fb2, dw1, db1, dw2, db2, scal);
  k_bwd7 <<<(CAP / 256) * 2, 256, 0, stream>>>(kb, kbT, gb, gbT, Msb, linvb, gdr8, grad, gradh);
  k_gcomb<<<GN_BLOCKS, 256, 0, stream>>>(grad, gradh, gnsqp);
  k_fin  <<<1, 256, 0, stream>>>(gnsqp, lossp, scal);
  k_upd  <<<(CAP * DMEM) / 256, 256, 0, stream>>>(mem, momS, grad, scal, out);
}

// Round 17
// 260.755 us; speedup vs baseline: 1.1156x; 1.1156x over previous
//
#include <hip/hip_runtime.h>
#include <math.h>

#define D_MODEL 1024
#define DMEM 64
#define CAP 65536
#define SEQ 1024
#define NTOT 2048      // B*S
#define GATE_H 32
#define THETA 0.01f
#define ISQD 0.125f    // 1/sqrt(64)
#define LOG2E 1.4426950408889634f
#define LN2 0.6931471805599453f
#define NSPLIT 16
#define CSPL (CAP / NSPLIT)    // 4096
#define GN_BLOCKS 2048         // gcomb partials

// fused k_pre block ranges
#define PRE_POOL_N 8
#define PRE_PACKM_N (CAP / 64)        // 1024
#define PRE_PROJ_N (NTOT / 4)         // 512
#define PRE_PACKM_BASE PRE_POOL_N
#define PRE_PROJ_BASE (PRE_POOL_N + PRE_PACKM_N)
#define PRE_TOTAL (PRE_POOL_N + PRE_PACKM_N + PRE_PROJ_N)

typedef float f32x4 __attribute__((ext_vector_type(4)));
typedef short bf16x8 __attribute__((ext_vector_type(8)));
typedef unsigned int u32x4 __attribute__((ext_vector_type(4)));
typedef unsigned int u32x2 __attribute__((ext_vector_type(2)));

#define MFMA16(a, b, c) __builtin_amdgcn_mfma_f32_16x16x32_bf16(a, b, c, 0, 0, 0)

__device__ inline unsigned short f2bf(float f) {
  union { float f; unsigned u; } v; v.f = f;
  unsigned r = v.u + 0x7FFFu + ((v.u >> 16) & 1u);
  return (unsigned short)(r >> 16);
}
__device__ inline unsigned cvtpk(float lo, float hi) {
  unsigned r;
  asm("v_cvt_pk_bf16_f32 %0, %1, %2" : "=v"(r) : "v"(lo), "v"(hi));
  return r;
}
__device__ inline float exp2i(float x) {
  float r;
  asm("v_exp_f32 %0, %1" : "=v"(r) : "v"(x));
  return r;
}

// ---------------- K_pre: fused pool | packm | proj (verified R15) ------
__global__ __launch_bounds__(256) void k_pre(const float* __restrict__ x,
    const float* __restrict__ mem,
    const float* __restrict__ Wk, const float* __restrict__ bk,
    const float* __restrict__ Wv, const float* __restrict__ bv,
    float* __restrict__ pooled, float* __restrict__ vout,
    unsigned short* __restrict__ kb, unsigned short* __restrict__ kbT,
    unsigned short* __restrict__ Msb, unsigned short* __restrict__ MsbT) {
  __shared__ __align__(16) char smem[16384];
  int tid = threadIdx.x;
  int bid = blockIdx.x;

  if (bid < PRE_POOL_N) {
    // ---- pool ----
    int idx = bid * 256 + tid;
    int b = idx >> 10, j = idx & 1023;
    const float* base = x + (size_t)b * SEQ * D_MODEL + j;
    float s = 0.f;
    for (int t = 0; t < SEQ; ++t) s += base[(size_t)t * D_MODEL];
    pooled[idx] = s * (1.0f / SEQ);
    return;
  }

  if (bid < PRE_PROJ_BASE) {
    // ---- packm ----
    short (*tile)[72] = (short(*)[72])smem;   // [64][72] = 9216 B
    int c0 = (bid - PRE_PACKM_BASE) * 64;
    int r = tid >> 2, dp = (tid & 3) * 16;
    const float4* src = (const float4*)(mem + (size_t)(c0 + r) * DMEM + dp);
    float4 q0 = src[0], q1 = src[1], q2 = src[2], q3 = src[3];
    float va[16] = {q0.x, q0.y, q0.z, q0.w, q1.x, q1.y, q1.z, q1.w,
                    q2.x, q2.y, q2.z, q2.w, q3.x, q3.y, q3.z, q3.w};
    const float s1 = ISQD * LOG2E;
    union { unsigned short s[16]; u32x4 v[2]; } o;
#pragma unroll
    for (int j = 0; j < 16; ++j) o.s[j] = f2bf(va[j] * s1);
    *(u32x4*)(Msb + (size_t)(c0 + r) * DMEM + dp) = o.v[0];
    *(u32x4*)(Msb + (size_t)(c0 + r) * DMEM + dp + 8) = o.v[1];
#pragma unroll
    for (int j = 0; j < 16; ++j) tile[dp + j][r] = (short)f2bf(va[j] * ISQD);
    __syncthreads();
    int d2 = tid >> 2, cp = (tid & 3) * 16;
    u32x4 t0 = *(const u32x4*)&tile[d2][cp];
    u32x4 t1 = *(const u32x4*)&tile[d2][cp + 8];
    *(u32x4*)(MsbT + (size_t)d2 * CAP + c0 + cp) = t0;
    *(u32x4*)(MsbT + (size_t)d2 * CAP + c0 + cp + 8) = t1;
    return;
  }

  // ---- proj ----
  float* xs = (float*)smem;   // [4*D_MODEL] = 16384 B
  int r = tid >> 6, j = tid & 63;
  int nb = (bid - PRE_PROJ_BASE) * 4;
  const float4* xr = (const float4*)(x + (size_t)nb * D_MODEL);
  float4* xs4 = (float4*)xs;
#pragma unroll
  for (int q = 0; q < 4; ++q) xs4[tid + 256 * q] = xr[tid + 256 * q];
  __syncthreads();
  float ak = bk[j], av = bv[j];
  const float* xrow = xs + r * D_MODEL;
#pragma unroll 8
  for (int i = 0; i < D_MODEL; ++i) {
    float xv = xrow[i];
    ak = fmaf(xv, Wk[i * DMEM + j], ak);
    av = fmaf(xv, Wv[i * DMEM + j], av);
  }
  int n = nb + r;
  vout[n * DMEM + j] = av;
  kb[n * DMEM + j] = f2bf(ak);
  kbT[(size_t)j * NTOT + n] = f2bf(ak * LN2);
}

// ---------------- K3: gates -> alpha, eta (4-wave parallel, verified R14) ----
__global__ __launch_bounds__(256) void k_gates(const float* __restrict__ pooled,
    const float* __restrict__ fw1, const float* __restrict__ fb1,
    const float* __restrict__ fw2, const float* __restrict__ fb2,
    const float* __restrict__ dw1, const float* __restrict__ db1,
    const float* __restrict__ dw2, const float* __restrict__ db2,
    float* __restrict__ scal) {
  __shared__ float hsh[2][2][GATE_H];
  __shared__ float outs[2][2];
  int t = threadIdx.x;
  int wv = t >> 6, lane = t & 63;
  int gate = wv >> 1, b = wv & 1;
  int h = lane & 31, half = lane >> 5;
  const float* w1 = gate ? dw1 : fw1;
  const float* b1 = gate ? db1 : fb1;
  const float* prow = pooled + b * D_MODEL;
  float z = 0.f;
  for (int i = half * 512; i < half * 512 + 512; ++i)
    z = fmaf(prow[i], w1[i * GATE_H + h], z);
  z += __shfl_xor(z, 32, 64);
  z += b1[h];
  float sig = 1.f / (1.f + __expf(-z));
  if (half == 0) hsh[gate][b][h] = z * sig;
  __syncthreads();
  if (t < 4) {
    int gg = t >> 1, bb = t & 1;
    const float* w2 = gg ? dw2 : fw2;
    float zz = gg ? db2[0] : fb2[0];
    for (int hh = 0; hh < GATE_H; ++hh) zz += hsh[gg][bb][hh] * w2[hh];
    outs[gg][bb] = 1.f / (1.f + __expf(-zz));
  }
  __syncthreads();
  if (t == 0) {
    scal[0] = 0.5f * (outs[0][0] + outs[0][1]);  // alpha
    scal[1] = 0.5f * (outs[1][0] + outs[1][1]);  // eta
  }
}

// ---------------- K4: MFMA forward v10 (verified R14/R15, NO setprio) --------
__global__ __launch_bounds__(256, 4) void k_fwd10(
    const unsigned short* __restrict__ kb,
    const unsigned short* __restrict__ Msb,
    const unsigned short* __restrict__ MsbT,
    float* __restrict__ l_s, float* __restrict__ r_s) {
  __shared__ __align__(16) char smem[35840];
  __shared__ float esh[4][32];
  short* Mt  = (short*)smem;                    // [128][72]
  short* MTt = Mt + 128 * 72;                   // [64][136]
  int tid = threadIdx.x;
  int wv = tid >> 6, lane = tid & 63;
  int u = lane >> 4, p = lane & 15;
  int sp = blockIdx.x & 15, ng = blockIdx.x >> 4;
  int n0 = ng * 32;

  bf16x8 bkf[2][2];
#pragma unroll
  for (int nf = 0; nf < 2; ++nf) {
    const unsigned short* kbase = kb + (size_t)(n0 + nf * 16 + p) * DMEM + u * 8;
    bkf[nf][0] = *(const bf16x8*)(kbase);
    bkf[nf][1] = *(const bf16x8*)(kbase + 32);
  }

  int mc = tid >> 3, mdh = tid & 7;
  int td = tid >> 4, tch = tid & 15;
  int c0base = sp * CSPL;
  u32x4 sM[4], sT[4];
#pragma unroll
  for (int q = 0; q < 4; ++q) {
    sM[q] = *(const u32x4*)(Msb + (size_t)(c0base + mc + 32 * q) * DMEM + mdh * 8);
    sT[q] = *(const u32x4*)(MsbT + (size_t)(td + 16 * q) * CAP + c0base + tch * 8);
  }

  f32x4 racc[4][2];
#pragma unroll
  for (int df = 0; df < 4; ++df)
#pragma unroll
    for (int nf = 0; nf < 2; ++nf) racc[df][nf] = (f32x4){0.f, 0.f, 0.f, 0.f};
  float esum0 = 0.f, esum1 = 0.f;

  int sA = ((u & 1) << 5) + p;
  int sB = sA + 16;
  bool hiCf = (u >= 2);

  const int NT = CSPL / 128;  // 32
  for (int it = 0; it < NT; ++it) {
    __syncthreads();
#pragma unroll
    for (int q = 0; q < 4; ++q) {
      *(u32x4*)(Mt + (mc + 32 * q) * 72 + mdh * 8) = sM[q];
      *(u32x4*)(MTt + (td + 16 * q) * 136 + tch * 8) = sT[q];
    }
    __syncthreads();
    int itn = (it + 1 < NT) ? it + 1 : it;
    int c0n = c0base + itn * 128;
#pragma unroll
    for (int q = 0; q < 4; ++q) {
      sM[q] = *(const u32x4*)(Msb + (size_t)(c0n + mc + 32 * q) * DMEM + mdh * 8);
      sT[q] = *(const u32x4*)(MsbT + (size_t)(td + 16 * q) * CAP + c0n + tch * 8);
    }
    f32x4 s[2][2];
#pragma unroll
    for (int cf = 0; cf < 2; ++cf) {
      bf16x8 a0 = *(const bf16x8*)(Mt + (wv * 32 + cf * 16 + p) * 72 + u * 8);
      bf16x8 a1 = *(const bf16x8*)(Mt + (wv * 32 + cf * 16 + p) * 72 + 32 + u * 8);
#pragma unroll
      for (int nf = 0; nf < 2; ++nf) {
        f32x4 acc = (f32x4){0.f, 0.f, 0.f, 0.f};
        acc = MFMA16(a0, bkf[nf][0], acc);
        acc = MFMA16(a1, bkf[nf][1], acc);
        s[cf][nf] = acc;
      }
    }
    bf16x8 aTf[4];
#pragma unroll
    for (int df = 0; df < 4; ++df)
      aTf[df] = *(const bf16x8*)(MTt + (df * 16 + p) * 136 + wv * 32 + u * 8);
#pragma unroll
    for (int nf = 0; nf < 2; ++nf) {
      unsigned q0t0, q0t1, q1t0, q1t1;
      {
        float e0 = exp2i(s[0][nf].x), e1 = exp2i(s[0][nf].y);
        float e2 = exp2i(s[0][nf].z), e3 = exp2i(s[0][nf].w);
        float t4 = (e0 + e1) + (e2 + e3);
        if (nf == 0) esum0 += t4; else esum1 += t4;
        q0t0 = cvtpk(e0, e1); q0t1 = cvtpk(e2, e3);
      }
      {
        float e0 = exp2i(s[1][nf].x), e1 = exp2i(s[1][nf].y);
        float e2 = exp2i(s[1][nf].z), e3 = exp2i(s[1][nf].w);
        float t4 = (e0 + e1) + (e2 + e3);
        if (nf == 0) esum0 += t4; else esum1 += t4;
        q1t0 = cvtpk(e0, e1); q1t1 = cvtpk(e2, e3);
      }
      unsigned a0 = (unsigned)__shfl((int)q0t0, sA, 64);
      unsigned a1 = (unsigned)__shfl((int)q0t1, sA, 64);
      unsigned a2 = (unsigned)__shfl((int)q0t0, sB, 64);
      unsigned a3 = (unsigned)__shfl((int)q0t1, sB, 64);
      unsigned b0 = (unsigned)__shfl((int)q1t0, sA, 64);
      unsigned b1 = (unsigned)__shfl((int)q1t1, sA, 64);
      unsigned b2 = (unsigned)__shfl((int)q1t0, sB, 64);
      unsigned b3 = (unsigned)__shfl((int)q1t1, sB, 64);
      u32x4 bw4 = {hiCf ? b0 : a0, hiCf ? b1 : a1,
                   hiCf ? b2 : a2, hiCf ? b3 : a3};
      bf16x8 w = __builtin_bit_cast(bf16x8, bw4);
#pragma unroll
      for (int df = 0; df < 4; ++df)
        racc[df][nf] = MFMA16(aTf[df], w, racc[df][nf]);
    }
  }

  esum0 += __shfl_xor(esum0, 16, 64);
  esum0 += __shfl_xor(esum0, 32, 64);
  esum1 += __shfl_xor(esum1, 16, 64);
  esum1 += __shfl_xor(esum1, 32, 64);
  if (u == 0) {
    esh[wv][p] = esum0;
    esh[wv][16 + p] = esum1;
  }
  __syncthreads();
  if (tid < 32) {
    float l = (esh[0][tid] + esh[1][tid]) + (esh[2][tid] + esh[3][tid]);
    l_s[sp * NTOT + n0 + tid] = l;
  }
  float* rt = (float*)smem;  // [4][64][33] = 33792 <= 35840
#pragma unroll
  for (int df = 0; df < 4; ++df)
#pragma unroll
    for (int nf = 0; nf < 2; ++nf)
#pragma unroll
      for (int r = 0; r < 4; ++r)
        rt[(wv * 64 + df * 16 + 4 * u + r) * 33 + nf * 16 + p] = racc[df][nf][r];
  __syncthreads();
  int n = tid >> 3;
  int d8 = (tid & 7) * 8;
  float o[8];
#pragma unroll
  for (int q = 0; q < 8; ++q)
    o[q] = (rt[(0 * 64 + d8 + q) * 33 + n] + rt[(1 * 64 + d8 + q) * 33 + n]) +
           (rt[(2 * 64 + d8 + q) * 33 + n] + rt[(3 * 64 + d8 + q) * 33 + n]);
  float* dst = r_s + ((size_t)sp * NTOT + n0 + n) * DMEM + d8;
  *(float4*)(dst) = (float4){o[0], o[1], o[2], o[3]};
  *(float4*)(dst + 4) = (float4){o[4], o[5], o[6], o[7]};
}

// ---------------- K5: combine splits, loss, g (bf16), gdotr ----------------
__global__ __launch_bounds__(256) void k_comb(
    const float* __restrict__ l_s, const float* __restrict__ r_s,
    const float* __restrict__ v,
    unsigned short* __restrict__ gb, unsigned short* __restrict__ gbT,
    float* __restrict__ gdr8, float* __restrict__ linv,
    float* __restrict__ lossp) {
  __shared__ float lsum[4];
  int tid = threadIdx.x;
  int nl = tid >> 6, dd = tid & 63;
  int n = blockIdx.x * 4 + nl;
  float l = 0.f;
#pragma unroll
  for (int s = 0; s < NSPLIT; ++s) l += l_s[s * NTOT + n];
  float r = 0.f;
#pragma unroll
  for (int s = 0; s < NSPLIT; ++s)
    r += r_s[((size_t)s * NTOT + n) * DMEM + dd];
  float li = 1.f / l;
  float ret = r * li * 8.0f;   // MsbT carried ISQD -> compensate exactly
  float vv = v[n * DMEM + dd];
  const float c0 = 2.f / (float)(NTOT * DMEM);
  float diff = ret - vv;
  float gv = c0 * diff;
  gb[n * DMEM + dd] = f2bf(gv);
  gbT[dd * NTOT + n] = f2bf(gv);
  float gr = gv * ret;
  float lp = diff * diff;
#pragma unroll
  for (int off = 1; off < 64; off <<= 1) {
    gr += __shfl_xor(gr, off, 64);
    lp += __shfl_xor(lp, off, 64);
  }
  if (dd == 0) {
    gdr8[n] = gr * (ISQD * LOG2E);
    linv[n] = li;
    lsum[nl] = lp;
  }
  __syncthreads();
  if (tid == 0)
    lossp[blockIdx.x] =
        (lsum[0] + lsum[1] + lsum[2] + lsum[3]) * (1.f / (float)(NTOT * DMEM));
}

// ---------------- K6: MFMA backward v7 (verified R10, NO setprio) -------
__global__ __launch_bounds__(256, 2) void k_bwd7(
    const unsigned short* __restrict__ kb, const unsigned short* __restrict__ kbT,
    const unsigned short* __restrict__ gb, const unsigned short* __restrict__ gbT,
    const unsigned short* __restrict__ Msb,
    const float* __restrict__ linv, const float* __restrict__ gdr8,
    float* __restrict__ gradf, unsigned short* __restrict__ gradh) {
  __shared__ __align__(16) short kt[32][72];
  __shared__ __align__(16) short gt[32][72];
  __shared__ __align__(16) short tT[2][64][40];   // [ktT, gtT]
  __shared__ unsigned wct[4][2][1280];            // per-wave [64c][20] w / coef
  int tid = threadIdx.x;
  int wv = tid >> 6, lane = tid & 63;
  int u = lane >> 4, p = lane & 15;
  int half = blockIdx.x & 1;
  int cw = (blockIdx.x >> 1) * 256 + wv * 64;
  int nbase = half * (NTOT / 2);
  unsigned* wtp = wct[wv][0];
  unsigned* ctp = wct[wv][1];

  bf16x8 bM[4][2];
#pragma unroll
  for (int cf = 0; cf < 4; ++cf) {
    const unsigned short* mb = Msb + (size_t)(cw + cf * 16 + p) * DMEM + u * 8;
    bM[cf][0] = *(const bf16x8*)(mb);
    bM[cf][1] = *(const bf16x8*)(mb + 32);
  }

  f32x4 gacc[4][4];
#pragma unroll
  for (int cf = 0; cf < 4; ++cf)
#pragma unroll
    for (int df = 0; df < 4; ++df) gacc[cf][df] = (f32x4){0.f, 0.f, 0.f, 0.f};

  int sn = tid >> 3, sdh = tid & 7;
  int sd = tid >> 2, sch = tid & 3;

  u32x4 rk  = *(const u32x4*)(kb + (size_t)(nbase + sn) * DMEM + sdh * 8);
  u32x4 rg  = *(const u32x4*)(gb + (size_t)(nbase + sn) * DMEM + sdh * 8);
  u32x4 rkT = *(const u32x4*)(kbT + (size_t)sd * NTOT + nbase + sch * 8);
  u32x4 rgT = *(const u32x4*)(gbT + (size_t)sd * NTOT + nbase + sch * 8);

  const int NT = (NTOT / 2) / 32;  // 32
  for (int it = 0; it < NT; ++it) {
    int n0 = nbase + it * 32;
    __syncthreads();
    *(u32x4*)&kt[sn][sdh * 8] = rk;
    *(u32x4*)&gt[sn][sdh * 8] = rg;
    *(u32x4*)&tT[0][sd][sch * 8] = rkT;
    *(u32x4*)&tT[1][sd][sch * 8] = rgT;
    __syncthreads();
    {
      int n0n = (it + 1 < NT) ? n0 + 32 : n0;
      rk  = *(const u32x4*)(kb + (size_t)(n0n + sn) * DMEM + sdh * 8);
      rg  = *(const u32x4*)(gb + (size_t)(n0n + sn) * DMEM + sdh * 8);
      rkT = *(const u32x4*)(kbT + (size_t)sd * NTOT + n0n + sch * 8);
      rgT = *(const u32x4*)(gbT + (size_t)sd * NTOT + n0n + sch * 8);
    }
    asm volatile("" ::: "memory");
#pragma unroll
    for (int nf = 0; nf < 2; ++nf) {
      bf16x8 ka0 = *(const bf16x8*)&kt[nf * 16 + p][u * 8];
      bf16x8 ka1 = *(const bf16x8*)&kt[nf * 16 + p][u * 8 + 32];
      bf16x8 ga0 = *(const bf16x8*)&gt[nf * 16 + p][u * 8];
      bf16x8 ga1 = *(const bf16x8*)&gt[nf * 16 + p][u * 8 + 32];
      float4 lv = *(const float4*)(linv + n0 + nf * 16 + u * 4);
      float4 dv = *(const float4*)(gdr8 + n0 + nf * 16 + u * 4);
#pragma unroll
      for (int cf = 0; cf < 4; ++cf) {
        f32x4 s = (f32x4){0.f, 0.f, 0.f, 0.f};
        s = MFMA16(ka0, bM[cf][0], s);
        s = MFMA16(ka1, bM[cf][1], s);
        f32x4 pg = (f32x4){0.f, 0.f, 0.f, 0.f};
        pg = MFMA16(ga0, bM[cf][0], pg);
        pg = MFMA16(ga1, bM[cf][1], pg);
        float w0 = exp2i(s.x) * lv.x;
        float w1 = exp2i(s.y) * lv.y;
        float w2 = exp2i(s.z) * lv.z;
        float w3 = exp2i(s.w) * lv.w;
        float c0v = w0 * (pg.x - dv.x);
        float c1v = w1 * (pg.y - dv.y);
        float c2v = w2 * (pg.z - dv.z);
        float c3v = w3 * (pg.w - dv.w);
        wtp[(cf * 16 + p) * 20 + nf * 8 + 2 * u]     = cvtpk(w0, w1);
        wtp[(cf * 16 + p) * 20 + nf * 8 + 2 * u + 1] = cvtpk(w2, w3);
        ctp[(cf * 16 + p) * 20 + nf * 8 + 2 * u]     = cvtpk(c0v, c1v);
        ctp[(cf * 16 + p) * 20 + nf * 8 + 2 * u + 1] = cvtpk(c2v, c3v);
      }
    }
    asm volatile("" ::: "memory");
    u32x4 aw4[4], ac4[4];
#pragma unroll
    for (int cf = 0; cf < 4; ++cf) {
      aw4[cf] = *(const u32x4*)(wtp + (cf * 16 + p) * 20 + u * 4);
      ac4[cf] = *(const u32x4*)(ctp + (cf * 16 + p) * 20 + u * 4);
    }
    asm volatile("" ::: "memory");
#pragma unroll
    for (int df = 0; df < 4; ++df) {
      bf16x8 bg = *(const bf16x8*)&tT[1][df * 16 + p][u * 8];
      bf16x8 bk2 = *(const bf16x8*)&tT[0][df * 16 + p][u * 8];
#pragma unroll
      for (int cf = 0; cf < 4; ++cf) {
        gacc[cf][df] = MFMA16(__builtin_bit_cast(bf16x8, aw4[cf]), bg, gacc[cf][df]);
        gacc[cf][df] = MFMA16(__builtin_bit_cast(bf16x8, ac4[cf]), bk2, gacc[cf][df]);
      }
    }
  }

  if (half == 0) {
#pragma unroll
    for (int cf = 0; cf < 4; ++cf)
#pragma unroll
      for (int df = 0; df < 4; ++df)
#pragma unroll
        for (int r = 0; r < 4; ++r)
          gradf[(size_t)(cw + cf * 16 + 4 * u + r) * DMEM + df * 16 + p] =
              gacc[cf][df][r];
  } else {
#pragma unroll
    for (int cf = 0; cf < 4; ++cf)
#pragma unroll
      for (int df = 0; df < 4; ++df)
#pragma unroll
        for (int r = 0; r < 4; ++r)
          gradh[(size_t)(cw + cf * 16 + 4 * u + r) * DMEM + df * 16 + p] =
              f2bf(gacc[cf][df][r]);
  }
}

// ---------------- K6b: grad = gradf + gradh; gnsq partials (verified R10) ----
__global__ __launch_bounds__(256) void k_gcomb(float* __restrict__ grad,
                                               const unsigned short* __restrict__ gradh,
                                               float* __restrict__ gnsqp) {
  __shared__ float red[4];
  int tid = threadIdx.x;
  size_t base = (size_t)blockIdx.x * 2048 + tid;
  float ss = 0.f;
#pragma unroll
  for (int j = 0; j < 8; ++j) {
    size_t i = base + (size_t)j * 256;
    unsigned hv = ((unsigned)gradh[i]) << 16;
    float v = grad[i] + __builtin_bit_cast(float, hv);
    grad[i] = v;
    ss = fmaf(v, v, ss);
  }
#pragma unroll
  for (int off = 1; off < 64; off <<= 1) ss += __shfl_xor(ss, off, 64);
  if ((tid & 63) == 0) red[tid >> 6] = ss;
  __syncthreads();
  if (tid == 0) gnsqp[blockIdx.x] = (red[0] + red[1]) + (red[2] + red[3]);
}

// ---------------- K7: final scalar reduce ----------------
__global__ __launch_bounds__(256) void k_fin(const float* __restrict__ gnsqp,
                                             const float* __restrict__ lossp,
                                             float* __restrict__ scal) {
  __shared__ float sh[8];
  int tid = threadIdx.x;
  float s1 = 0.f, s2 = 0.f;
  for (int i = tid; i < GN_BLOCKS; i += 256) s1 += gnsqp[i];
  for (int i = tid; i < NTOT / 4; i += 256) s2 += lossp[i];
#pragma unroll
  for (int off = 1; off < 64; off <<= 1) {
    s1 += __shfl_xor(s1, off, 64);
    s2 += __shfl_xor(s2, off, 64);
  }
  if ((tid & 63) == 0) { sh[(tid >> 6) * 2] = s1; sh[(tid >> 6) * 2 + 1] = s2; }
  __syncthreads();
  if (tid == 0) {
    float gnsq = sh[0] + sh[2] + sh[4] + sh[6];
    float loss = sh[1] + sh[3] + sh[5] + sh[7];
    float gn = sqrtf(gnsq);
    float clip = (gn > 1.0f) ? (1.0f / gn) : 1.0f;
    scal[2] = THETA * clip;
    scal[3] = loss;
  }
}

// ---------------- K8: M_new / S_new / loss write ----------------
__global__ __launch_bounds__(256) void k_upd(const float* __restrict__ mem,
    const float* __restrict__ momS, const float* __restrict__ grad,
    const float* __restrict__ scal, float* __restrict__ dout) {
  size_t i = (size_t)blockIdx.x * 256 + threadIdx.x;
  float oma = 1.f - scal[0];
  float eta = scal[1];
  float th = scal[2];
  if (i == 0) dout[0] = scal[3];
  float gr = grad[i];
  float sn = fmaf(-th, gr, eta * momS[i]);
  dout[1 + (size_t)CAP * DMEM + i] = sn;       // S_new (in-place over grad)
  dout[1 + i] = fmaf(oma, mem[i], sn);         // M_new
}

extern "C" void kernel_launch(void* const* d_in, const int* in_sizes, int n_in,
                              void* d_out, int out_size, void* d_ws, size_t ws_size,
                              hipStream_t stream) {
  const float* x    = (const float*)d_in[0];
  const float* mem  = (const float*)d_in[1];
  const float* momS = (const float*)d_in[2];
  const float* Wk   = (const float*)d_in[3];
  const float* bk   = (const float*)d_in[4];
  const float* Wv   = (const float*)d_in[5];
  const float* bv   = (const float*)d_in[6];
  const float* fw1  = (const float*)d_in[7];
  const float* fb1  = (const float*)d_in[8];
  const float* fw2  = (const float*)d_in[9];
  const float* fb2  = (const float*)d_in[10];
  const float* dw1  = (const float*)d_in[11];
  const float* db1  = (const float*)d_in[12];
  const float* dw2  = (const float*)d_in[13];
  const float* db2  = (const float*)d_in[14];

  float* out = (float*)d_out;
  float* wsf = (float*)d_ws;

  // ws scratch (~1.6 MB)
  float* scal   = wsf;                    // 16
  float* pooled = wsf + 16;               // 2048
  float* vbuf   = wsf + 2064;             // 131072
  float* gdr8   = vbuf + 131072;          // 2048
  float* linvb  = gdr8 + 2048;            // 2048
  float* lsb    = linvb + 2048;           // NSPLIT*2048 = 32768
  float* lossp  = lsb + 32768;            // 512
  float* gnsqp  = lossp + 512;            // 2048
  unsigned short* kb  = (unsigned short*)(gnsqp + 2048);  // 131072 shorts each
  unsigned short* kbT = kb + 131072;
  unsigned short* gb  = kbT + 131072;
  unsigned short* gbT = gb + 131072;

  // Msb+MsbT at out+0 (loss written last by k_upd) -> gradh (aliasing dead
  // MsbT) never overlaps grad.
  unsigned short* Msb   = (unsigned short*)out;          // [c][d], 8 MB
  unsigned short* MsbT  = Msb + (size_t)CAP * DMEM;      // [d][c], 8 MB
  unsigned short* gradh = MsbT;                          // bf16 half1 grad (reuse)
  // S_new slot: r_s (8 MB, dead before grad), then grad
  float* rsb  = out + 4 + (size_t)CAP * DMEM + 4;        // 16 splits * 2048 * 64
  float* grad = out + 1 + (size_t)CAP * DMEM;

  k_pre  <<<PRE_TOTAL, 256, 0, stream>>>(x, mem, Wk, bk, Wv, bv,
                                         pooled, vbuf, kb, kbT, Msb, MsbT);
  k_gates<<<1, 256, 0, stream>>>(pooled, fw1, fb1, fw2, fb2, dw1, db1, dw2, db2, scal);
  k_fwd10<<<(NTOT / 32) * NSPLIT, 256, 0, stream>>>(kb, Msb, MsbT, lsb, rsb);
  k_comb <<<NTOT / 4, 256, 0, stream>>>(lsb, rsb, vbuf, gb, gbT, gdr8, linvb, lossp);
  k_bwd7 <<<(CAP / 256) * 2, 256, 0, stream>>>(kb, kbT, gb, gbT, Msb, linvb, gdr8, grad, gradh);
  k_gcomb<<<GN_BLOCKS, 256, 0, stream>>>(grad, gradh, gnsqp);
  k_fin  <<<1, 256, 0, stream>>>(gnsqp, lossp, scal);
  k_upd  <<<(CAP * DMEM) / 256, 256, 0, stream>>>(mem, momS, grad, scal, out);
}